// Round 5
// baseline (13557.852 us; speedup 1.0000x reference)
//
#include <hip/hip_runtime.h>
#include <stdint.h>

// Problem constants (match reference)
#define B 128
#define S 256
#define T 256
#define EMBED 256
#define ENC 256
#define DEC 512
#define DOF 4

typedef __attribute__((ext_vector_type(8))) short bf16x8;   // 8 bf16 = 4 VGPRs (MFMA A/B frag)
typedef __attribute__((ext_vector_type(4))) float f32x4;    // MFMA C/D frag

static __device__ __forceinline__ float bf2f(unsigned short u){
  union{uint32_t u;float f;}c; c.u = ((uint32_t)u)<<16; return c.f;
}
static __device__ __forceinline__ unsigned short f2bf(float f){
  union{float f;uint32_t u;}c; c.f=f; uint32_t u=c.u;
  u += 0x7fffu + ((u>>16)&1u);  // round-to-nearest-even
  return (unsigned short)(u>>16);
}
static __device__ __forceinline__ void unp2(uint32_t w, float&a, float&b){
  union{uint32_t u;float f;}c1,c2; c1.u = w<<16; c2.u = w & 0xffff0000u; a=c1.f; b=c2.f;
}
static __device__ __forceinline__ float sigm(float x){ return 1.0f/(1.0f+__expf(-x)); }

// ---------------------------------------------------------------------------
// Coherent (agent-scope, cache-bypassing) accessors for cross-block state.
// Read-only data (weights, encOut, win, emb) uses NORMAL cached loads.
// ---------------------------------------------------------------------------
static __device__ __forceinline__ unsigned long long ldc8(const void* p){
  return __hip_atomic_load((unsigned long long*)p, __ATOMIC_RELAXED, __HIP_MEMORY_SCOPE_AGENT);
}
static __device__ __forceinline__ void stc8(void* p, unsigned long long v){
  __hip_atomic_store((unsigned long long*)p, v, __ATOMIC_RELAXED, __HIP_MEMORY_SCOPE_AGENT);
}
static __device__ __forceinline__ void stc4(void* p, unsigned v){
  __hip_atomic_store((unsigned*)p, v, __ATOMIC_RELAXED, __HIP_MEMORY_SCOPE_AGENT);
}
static __device__ __forceinline__ unsigned ldc4(const void* p){
  return __hip_atomic_load((const unsigned*)p, __ATOMIC_RELAXED, __HIP_MEMORY_SCOPE_AGENT);
}
static __device__ __forceinline__ void stc4f(float* p, float v){ stc4(p, __float_as_uint(v)); }
static __device__ __forceinline__ float ldc4f(const float* p){ return __uint_as_float(ldc4(p)); }
union F16x8 { unsigned long long q[2]; bf16x8 v; unsigned short s[8]; };
union Ubf   { bf16x8 v; uint32_t u[4]; unsigned short s[8]; };
static __device__ __forceinline__ bf16x8 ldfrag_c(const unsigned short* p){
  F16x8 u; u.q[0] = ldc8(p); u.q[1] = ldc8(p + 4); return u.v;
}
static __device__ __forceinline__ unsigned long long pack4bf(float a,float b,float c,float d){
  return (unsigned long long)f2bf(a) | ((unsigned long long)f2bf(b)<<16)
       | ((unsigned long long)f2bf(c)<<32) | ((unsigned long long)f2bf(d)<<48);
}

// ---------------------------------------------------------------------------
// Two-level device barrier. Arrivals: fetch_add on one of 16 spread L1 lines;
// the per-line last arriver adds to the single L2 counter. Waiters: ONE lane
// polls the L2 counter (>= 16*epoch) with sleep backoff. RMW lines and the
// polled line are distinct for L1, and the L2 line sees only 16 RMW/epoch —
// poll reads no longer queue ahead of arrivals.
// ---------------------------------------------------------------------------
#define CLINE 32   // u32 per counter line (128 B)
#define BAR_A   0
#define BAR_C   18
#define BAR_F   36
#define BAR_ENC 64   // 4 domains x 18 lines

static __device__ __forceinline__ void bar_pub(unsigned* base, int line,
                                               unsigned perline, unsigned epoch){
  __builtin_amdgcn_s_waitcnt(0);     // drain this wave's coherent stores
  __syncthreads();                   // all waves drained
  if (threadIdx.x == 0){
    unsigned old = __hip_atomic_fetch_add(base + (size_t)line*CLINE, 1u,
                                          __ATOMIC_RELAXED, __HIP_MEMORY_SCOPE_AGENT);
    if (old + 1u == perline*epoch)
      __hip_atomic_fetch_add(base + (size_t)16*CLINE, 1u,
                             __ATOMIC_RELAXED, __HIP_MEMORY_SCOPE_AGENT);
  }
}
static __device__ __forceinline__ void bar_wait(unsigned* base, unsigned epoch){
  if (threadIdx.x == 0){
    while (__hip_atomic_load(base + (size_t)16*CLINE,
                             __ATOMIC_RELAXED, __HIP_MEMORY_SCOPE_AGENT) < 16u*epoch)
      __builtin_amdgcn_s_sleep(4);
  }
  __syncthreads();
  asm volatile("" ::: "memory");
}

// swizzled LDS index (in shorts) for encS: row s (0..255), 16B-chunk c (0..31)
static __device__ __forceinline__ int enc_idx(int s, int c){
  return s*256 + (((c & 24) | ((c ^ s) & 7)) << 3);
}

// ---------------------------------------------------------------------------
// Persistent bi-LSTM encoder. Grid 256 = dir(2) x mg(2) x ng(64).
// Weight frags (16 x bf16x8 = 64 VGPR) persist in registers all 256 steps;
// c in registers. 4 independent (dir,mg) barrier domains.
// ---------------------------------------------------------------------------
__global__ __launch_bounds__(256,1) void k_encoder(
  const unsigned short* __restrict__ emb,   // (S,B,256)
  const unsigned short* __restrict__ WFx, const unsigned short* __restrict__ WBx,
  const float* __restrict__ bF, const float* __restrict__ bB,
  unsigned short* __restrict__ hEnc,        // [dir][2][B][256]
  unsigned short* __restrict__ encOut,      // [B][S][512]
  unsigned* __restrict__ cnts)
{
  __shared__ __align__(16) float Gs[64*17];
  __shared__ float bsh[16];
  const int bid = blockIdx.x;
  const int dir = bid >> 7;
  const int mg  = (bid >> 6) & 1;
  const int ng  = bid & 63;
  const int tid = threadIdx.x;
  const int lane = tid & 63, w = tid >> 6;
  const int l16 = lane & 15, qd = lane >> 4;
  const int m_base = mg * 64;
  unsigned* base = cnts + (size_t)(BAR_ENC + (dir*2 + mg)*18)*CLINE;

  // persistent weight fragments
  const unsigned short* Bp = (dir ? WBx : WFx) + (size_t)ng*16*512 + (size_t)lane*8;
  bf16x8 Bv[16];
#pragma unroll
  for (int ks = 0; ks < 16; ++ks) Bv[ks] = *(const bf16x8*)(Bp + (size_t)ks*512);
  if (tid < 16) bsh[tid] = (dir ? bB : bF)[ng*16 + tid];
  float c[4] = {0.f,0.f,0.f,0.f};
  __syncthreads();

  for (int t = 0; t < S; ++t){
    const int tt = dir ? (S-1-t) : t;
    const unsigned short* Ae = emb + ((size_t)tt*B + m_base + w*16 + l16)*256 + qd*8;
    bf16x8 av[8];
#pragma unroll
    for (int ks = 0; ks < 8; ++ks) av[ks] = *(const bf16x8*)(Ae + ks*32);   // cached prefetch
    if (t) bar_wait(base, (unsigned)t);
    const unsigned short* Ah = hEnc + (((size_t)dir*2 + (size_t)(t&1))*B + m_base + w*16 + l16)*256 + qd*8;
    bf16x8 hf[8];
#pragma unroll
    for (int ks = 0; ks < 8; ++ks) hf[ks] = ldfrag_c(Ah + ks*32);
    f32x4 acc = (f32x4){0.f,0.f,0.f,0.f};
#pragma unroll
    for (int ks = 0; ks < 8; ++ks)
      acc = __builtin_amdgcn_mfma_f32_16x16x32_bf16(av[ks], Bv[ks], acc, 0, 0, 0);
#pragma unroll
    for (int ks = 0; ks < 8; ++ks)
      acc = __builtin_amdgcn_mfma_f32_16x16x32_bf16(hf[ks], Bv[8+ks], acc, 0, 0, 0);
    __syncthreads();
#pragma unroll
    for (int r = 0; r < 4; ++r)
      Gs[(w*16 + qd*4 + r)*17 + l16] = acc[r];
    __syncthreads();
    if (tid < 64){
      float hv[4];
#pragma unroll
      for (int u = 0; u < 4; ++u){
        const float gi = Gs[tid*17 + u*4 + 0] + bsh[u*4 + 0];
        const float gf = Gs[tid*17 + u*4 + 1] + bsh[u*4 + 1];
        const float gg = Gs[tid*17 + u*4 + 2] + bsh[u*4 + 2];
        const float go = Gs[tid*17 + u*4 + 3] + bsh[u*4 + 3];
        const float cn = sigm(gf)*c[u] + sigm(gi)*tanhf(gg);
        c[u] = cn;
        hv[u] = sigm(go)*tanhf(cn);
      }
      const int b2 = m_base + tid;
      const unsigned long long hq = pack4bf(hv[0],hv[1],hv[2],hv[3]);
      stc8(&hEnc[(((size_t)dir*2 + (size_t)((t+1)&1))*B + b2)*256 + ng*4], hq);
      *(unsigned long long*)&encOut[((size_t)b2*S + tt)*512 + dir*256 + ng*4] = hq;
    }
    bar_pub(base, ng & 15, 4u, (unsigned)(t+1));
  }
}

// ---------------------------------------------------------------------------
// Persistent decoder. Grid 256; block i owns (batch b=i>>1, e-half eh=i&1),
// holds encOut[b,:,eh-half] swizzled in LDS (128 KB) all 256 steps.
// Gate weights (34 frags = 136 VGPR) persist in registers.
// Step: [waitF] gates -> barA -> [outproj overlap] -> waitA ->
//       attention (q matvec + scores + pair-flag + softmax + ctx) -> barC ->
//       [64 blocks: waitC -> feed -> barF].
// ---------------------------------------------------------------------------
__global__ __launch_bounds__(256,1) void k_decoder(
  const unsigned short* __restrict__ win,    // (T,B,64)
  const unsigned short* __restrict__ WDx,    // swizzled gates weights
  const float* __restrict__ bD,              // 2048 reordered
  const unsigned short* __restrict__ WCx,    // swizzled W_ctx
  const unsigned short* __restrict__ WQT,    // W_src^T interleaved for matvec
  const unsigned short* __restrict__ encOut, // (B,S,512)
  const int* __restrict__ in_seq,
  const float* __restrict__ Wout, const float* __restrict__ bout,
  unsigned short* __restrict__ hdec,         // [2][B][512]
  unsigned short* __restrict__ feed,         // [B][512]
  unsigned short* __restrict__ ctxb,         // [B][512]
  float* __restrict__ scp,                   // [B][2][256] partial scores
  unsigned* __restrict__ pf,                 // [B][2] pair epoch flags
  float* __restrict__ out_main, float* __restrict__ out_attn,
  unsigned* __restrict__ cnts)
{
  __shared__ __align__(16) unsigned short encS[65536];  // 128 KB resident tile
  __shared__ __align__(16) float scrf[1600];
  __shared__ float bsh[16];
  unsigned* barA = cnts + (size_t)BAR_A*CLINE;
  unsigned* barC = cnts + (size_t)BAR_C*CLINE;
  unsigned* barF = cnts + (size_t)BAR_F*CLINE;
  const int bid = blockIdx.x;
  const int b  = bid >> 1, eh = bid & 1;
  const int mg = bid & 1, ng = (bid >> 1) & 127;
  const int tid = threadIdx.x;
  const int lane = tid & 63, w = tid >> 6;
  const int l16 = lane & 15, qd = lane >> 4;
  const int m_base = mg*64;

  // ---- init: bias, mask, persistent gate weight frags, resident encOut tile
  if (tid < 16) bsh[tid] = bD[ng*16 + tid];
  const int mymask = (in_seq[b*S + tid] == 0);
  const unsigned short* Bp = WDx + (size_t)ng*34*512 + (size_t)lane*8;
  bf16x8 WBv[34];
#pragma unroll
  for (int ks = 0; ks < 34; ++ks) WBv[ks] = *(const bf16x8*)(Bp + (size_t)ks*512);
  for (int i = 0; i < 32; ++i){
    const int s = i*8 + (tid>>5), cc = tid & 31;
    const uint4 v = *(const uint4*)&encOut[((size_t)b*S + s)*512 + eh*256 + cc*8];
    *(uint4*)&encS[enc_idx(s, cc)] = v;
  }
  float c[4] = {0.f,0.f,0.f,0.f};
  const bool doFeed = ((bid & 3) == 3);
  const int  fblk = bid >> 2, fm = fblk >> 5, fn = fblk & 31;
  __syncthreads();

  for (int t = 0; t < T; ++t){
    const int row = m_base + w*16 + l16;
    const unsigned short* Aw = win + ((size_t)t*B + row)*64 + qd*8;
    bf16x8 wv0 = *(const bf16x8*)(Aw);         // cached prefetch (read-only)
    bf16x8 wv1 = *(const bf16x8*)(Aw + 32);
    if (t) bar_wait(barF, (unsigned)t);        // feed_{t-1} ready
    // ---------------- phase A: gates + LSTM update ----------------
    const unsigned short* Af = feed + (size_t)row*512 + qd*8;
    const unsigned short* Ah = hdec + ((size_t)(t&1)*B + row)*512 + qd*8;
    f32x4 acc = (f32x4){0.f,0.f,0.f,0.f};
    {
      bf16x8 av[17];
      av[0] = wv0; av[1] = wv1;
#pragma unroll
      for (int i = 0; i < 15; ++i) av[2+i] = ldfrag_c(Af + i*32);
#pragma unroll
      for (int ks = 0; ks < 17; ++ks)
        acc = __builtin_amdgcn_mfma_f32_16x16x32_bf16(av[ks], WBv[ks], acc, 0, 0, 0);
    }
    {
      bf16x8 av[17];
      av[0] = ldfrag_c(Af + 15*32);
#pragma unroll
      for (int i = 0; i < 16; ++i) av[1+i] = ldfrag_c(Ah + i*32);
#pragma unroll
      for (int ks = 0; ks < 17; ++ks)
        acc = __builtin_amdgcn_mfma_f32_16x16x32_bf16(av[ks], WBv[17+ks], acc, 0, 0, 0);
    }
    __syncthreads();
#pragma unroll
    for (int r = 0; r < 4; ++r)
      scrf[(w*16 + qd*4 + r)*17 + l16] = acc[r];
    __syncthreads();
    if (tid < 64){
      float hv[4];
#pragma unroll
      for (int u = 0; u < 4; ++u){
        const float gi = scrf[tid*17 + u*4 + 0] + bsh[u*4 + 0];
        const float gf = scrf[tid*17 + u*4 + 1] + bsh[u*4 + 1];
        const float gg = scrf[tid*17 + u*4 + 2] + bsh[u*4 + 2];
        const float go = scrf[tid*17 + u*4 + 3] + bsh[u*4 + 3];
        const float cn = sigm(gf)*c[u] + sigm(gi)*tanhf(gg);
        c[u] = cn;
        hv[u] = sigm(go)*tanhf(cn);
      }
      stc8(&hdec[((size_t)((t+1)&1)*B + m_base + tid)*512 + ng*4],
           pack4bf(hv[0],hv[1],hv[2],hv[3]));
    }
    bar_pub(barA, bid & 15, 16u, (unsigned)(t+1));

    // out-projection of feed_{t-1} (overlaps others' barA wait; odd blocks)
    if ((bid & 1) && t > 0){
      const int b2o = bid >> 1;
      const int d = tid >> 6, kk = lane;
      const unsigned short* fp = feed + (size_t)b2o*512 + kk*8;
      F16x8 u; u.q[0] = ldc8(fp); u.q[1] = ldc8(fp + 4);
      const float* wp = Wout + d*512 + kk*8;
      float p = 0.f;
#pragma unroll
      for (int j2 = 0; j2 < 8; ++j2) p += bf2f(u.s[j2]) * wp[j2];
#pragma unroll
      for (int off = 32; off > 0; off >>= 1) p += __shfl_down(p, off, 64);
      if (kk == 0){
        const float v = p + bout[d];
        out_main[((size_t)b2o*T + (t-1))*4 + d] = (d < 3) ? tanhf(v) : fmaxf(v, 0.f);
      }
    }

    // ---------------- attention (all blocks; e-half of batch b) ------------
    bar_wait(barA, (unsigned)(t+1));           // full h_t
    {  // stage h_t[b] (512) into LDS hsh = scrf[1024..1535]
      const unsigned short* hsrc = hdec + ((size_t)((t+1)&1)*B + b)*512;
      if (tid < 128){
        F16x8 u; u.q[0] = ldc8(hsrc + tid*4);
#pragma unroll
        for (int j2 = 0; j2 < 4; ++j2) scrf[1024 + tid*4 + j2] = bf2f(u.s[j2]);
      }
    }
    __syncthreads();
    {  // q matvec: thread computes q[e], e = eh*256 + tid  (W L2-hot, coalesced)
      float qv = 0.f;
      const int e = eh*256 + tid;
#pragma unroll 8
      for (int k8 = 0; k8 < 64; ++k8){
        Ubf u8; u8.v = *(const bf16x8*)&WQT[(size_t)(k8*512 + e)*8];
        float f0,f1,f2,f3,f4,f5,f6,f7;
        unp2(u8.u[0],f0,f1); unp2(u8.u[1],f2,f3); unp2(u8.u[2],f4,f5); unp2(u8.u[3],f6,f7);
        const float* hp = &scrf[1024 + k8*8];
        qv += f0*hp[0] + f1*hp[1] + f2*hp[2] + f3*hp[3]
            + f4*hp[4] + f5*hp[5] + f6*hp[6] + f7*hp[7];
      }
      scrf[tid] = qv;   // qsh
    }
    __syncthreads();
    float sc = 0.f;
#pragma unroll 8
    for (int cix = 0; cix < 32; ++cix){
      Ubf u8; u8.v = *(const bf16x8*)&encS[enc_idx(tid, cix)];
      float f0,f1,f2,f3,f4,f5,f6,f7;
      unp2(u8.u[0],f0,f1); unp2(u8.u[1],f2,f3); unp2(u8.u[2],f4,f5); unp2(u8.u[3],f6,f7);
      const float* qp = &scrf[cix*8];
      sc += f0*qp[0] + f1*qp[1] + f2*qp[2] + f3*qp[3]
          + f4*qp[4] + f5*qp[5] + f6*qp[6] + f7*qp[7];
    }
    stc4f(&scp[((size_t)b*2 + eh)*256 + tid], sc);
    // pair sync via single-writer epoch flags (no RMW)
    __builtin_amdgcn_s_waitcnt(0);
    __syncthreads();
    if (tid == 0){
      stc4(&pf[b*2 + eh], (unsigned)(t+1));
      while (ldc4(&pf[b*2 + (1-eh)]) < (unsigned)(t+1)) __builtin_amdgcn_s_sleep(2);
    }
    __syncthreads();
    asm volatile("" ::: "memory");
    float tot = sc + ldc4f(&scp[((size_t)b*2 + (1-eh))*256 + tid]);
    if (mymask) tot = -1e30f;
    // softmax over 256 s
    float mx = tot;
#pragma unroll
    for (int off = 32; off > 0; off >>= 1) mx = fmaxf(mx, __shfl_xor(mx, off, 64));
    if (lane == 0) scrf[512 + w] = mx;
    __syncthreads();
    mx = fmaxf(fmaxf(scrf[512], scrf[513]), fmaxf(scrf[514], scrf[515]));
    const float e = __expf(tot - mx);
    float l = e;
#pragma unroll
    for (int off = 32; off > 0; off >>= 1) l += __shfl_xor(l, off, 64);
    if (lane == 0) scrf[516 + w] = l;
    __syncthreads();
    l = scrf[516] + scrf[517] + scrf[518] + scrf[519];
    const float aw = e / l;
    scrf[256 + tid] = aw;
    if (eh == 0) __builtin_nontemporal_store(aw, &out_attn[((size_t)b*T + t)*S + tid]);
    __syncthreads();
    // ctx e-half: wave w covers 64 s rows (2/iter), lane owns 8-e chunk
    {
      float a[8] = {0,0,0,0,0,0,0,0};
      const int cc = lane & 31, par = lane >> 5;
      for (int i2 = 0; i2 < 32; ++i2){
        const int srow = w*64 + i2*2 + par;
        const float wgt = scrf[256 + srow];
        Ubf u8; u8.v = *(const bf16x8*)&encS[enc_idx(srow, cc)];
        float f0,f1,f2,f3,f4,f5,f6,f7;
        unp2(u8.u[0],f0,f1); unp2(u8.u[1],f2,f3); unp2(u8.u[2],f4,f5); unp2(u8.u[3],f6,f7);
        a[0]+=wgt*f0; a[1]+=wgt*f1; a[2]+=wgt*f2; a[3]+=wgt*f3;
        a[4]+=wgt*f4; a[5]+=wgt*f5; a[6]+=wgt*f6; a[7]+=wgt*f7;
      }
#pragma unroll
      for (int j2 = 0; j2 < 8; ++j2) a[j2] += __shfl_xor(a[j2], 32, 64);
      if (par == 0){
#pragma unroll
        for (int j2 = 0; j2 < 8; ++j2) scrf[528 + w*256 + cc*8 + j2] = a[j2];
      }
    }
    __syncthreads();
    if (tid < 128){
      const int e2 = tid*2;
      const float s0 = scrf[528+e2]   + scrf[528+256+e2]   + scrf[528+512+e2]   + scrf[528+768+e2];
      const float s1 = scrf[528+e2+1] + scrf[528+256+e2+1] + scrf[528+512+e2+1] + scrf[528+768+e2+1];
      stc4(&ctxb[(size_t)b*512 + eh*256 + e2],
           (unsigned)f2bf(s0) | ((unsigned)f2bf(s1) << 16));
    }
    bar_pub(barC, bid & 15, 16u, (unsigned)(t+1));

    // ---------------- phase F: feed = tanh([h|ctx] @ W_ctx^T) (64 blocks) ---
    if (doFeed){
      bar_wait(barC, (unsigned)(t+1));
      const int frow = fm*64 + w*16 + l16;
      const unsigned short* Fh = hdec + ((size_t)((t+1)&1)*B + frow)*512 + qd*8;
      const unsigned short* Fc = ctxb + (size_t)frow*512 + qd*8;
      const unsigned short* Bf = WCx + (size_t)fn*32*512 + (size_t)lane*8;
      f32x4 fa = (f32x4){0.f,0.f,0.f,0.f};
      {
        bf16x8 bv[16], av[16];
#pragma unroll
        for (int ks = 0; ks < 16; ++ks) bv[ks] = *(const bf16x8*)(Bf + (size_t)ks*512);
#pragma unroll
        for (int ks = 0; ks < 16; ++ks) av[ks] = ldfrag_c(Fh + ks*32);
#pragma unroll
        for (int ks = 0; ks < 16; ++ks)
          fa = __builtin_amdgcn_mfma_f32_16x16x32_bf16(av[ks], bv[ks], fa, 0, 0, 0);
      }
      {
        bf16x8 bv[16], av[16];
#pragma unroll
        for (int ks = 0; ks < 16; ++ks) bv[ks] = *(const bf16x8*)(Bf + (size_t)(16+ks)*512);
#pragma unroll
        for (int ks = 0; ks < 16; ++ks) av[ks] = ldfrag_c(Fc + ks*32);
#pragma unroll
        for (int ks = 0; ks < 16; ++ks)
          fa = __builtin_amdgcn_mfma_f32_16x16x32_bf16(av[ks], bv[ks], fa, 0, 0, 0);
      }
      __syncthreads();
#pragma unroll
      for (int r = 0; r < 4; ++r)
        scrf[(w*16 + qd*4 + r)*17 + l16] = tanhf(fa[r]);
      __syncthreads();
      if (tid < 64){
        const int fb = fm*64 + tid;
#pragma unroll
        for (int u = 0; u < 4; ++u)
          stc8(&feed[(size_t)fb*512 + fn*16 + u*4],
               pack4bf(scrf[tid*17+u*4+0], scrf[tid*17+u*4+1],
                       scrf[tid*17+u*4+2], scrf[tid*17+u*4+3]));
      }
      bar_pub(barF, (bid >> 2) & 15, 4u, (unsigned)(t+1));
    }
  }
  // final out-projection (feed_255)
  if (bid & 1){
    bar_wait(barF, 256u);
    const int b2o = bid >> 1;
    const int d = tid >> 6, kk = lane;
    const unsigned short* fp = feed + (size_t)b2o*512 + kk*8;
    F16x8 u; u.q[0] = ldc8(fp); u.q[1] = ldc8(fp + 4);
    const float* wp = Wout + d*512 + kk*8;
    float p = 0.f;
#pragma unroll
    for (int j2 = 0; j2 < 8; ++j2) p += bf2f(u.s[j2]) * wp[j2];
#pragma unroll
    for (int off = 32; off > 0; off >>= 1) p += __shfl_down(p, off, 64);
    if (kk == 0){
      const float v = p + bout[d];
      out_main[((size_t)b2o*T + 255)*4 + d] = (d < 3) ? tanhf(v) : fmaxf(v, 0.f);
    }
  }
}

// ---------------- setup / builder kernels ----------------
// encoder weights: reorder rows (j*4+g), swizzle to frag order
__global__ __launch_bounds__(256) void k_build_encw(
  const float* __restrict__ WihF, const float* __restrict__ WhhF,
  const float* __restrict__ WihB, const float* __restrict__ WhhB,
  unsigned short* WFx, unsigned short* WBx)
{
  const int idx = blockIdx.x*256 + threadIdx.x;     // 2*1024*512
  const int dir = idx >> 19;
  const int i2 = idx & 524287;
  const int r = i2 >> 9, k = i2 & 511;
  const int j = r >> 2, g = r & 3;
  const int orig = g*256 + j;
  const float* Wih = dir ? WihB : WihF;
  const float* Whh = dir ? WhhB : WhhF;
  const float v = (k < 256) ? Wih[orig*256 + k] : Whh[orig*256 + (k-256)];
  const int ng = r >> 4, l16 = r & 15;
  const int ks = k >> 5, qdd = (k >> 3) & 3, jj = k & 7;
  (dir ? WBx : WFx)[(((size_t)ng*16 + ks)*64 + qdd*16 + l16)*8 + jj] = f2bf(v);
}

// gates weights: reorder rows (j*4+g), pad cols to 1088, swizzle to frag order
__global__ __launch_bounds__(256) void k_build_decw(
  const float* __restrict__ Wih, const float* __restrict__ Whh, unsigned short* WDx)
{
  const int idx = blockIdx.x*256 + threadIdx.x;
  if (idx >= 2048*1088) return;
  const int row = idx / 1088, col = idx - row*1088;
  const int j = row >> 2, g = row & 3;
  const int orig = g*512 + j;
  float v;
  if (col < 16)        v = Wih[orig*528 + col];          // w_t part
  else if (col < 64)   v = 0.f;                          // pad
  else if (col < 576)  v = Wih[orig*528 + (col - 48)];   // feed part
  else                 v = Whh[orig*512 + (col - 576)];  // h part
  const int ng = row >> 4, l16 = row & 15;
  const int ks = col >> 5, qdd = (col >> 3) & 3, jj = col & 7;
  WDx[(((size_t)ng*34 + ks)*64 + qdd*16 + l16)*8 + jj] = f2bf(v);
}

__global__ __launch_bounds__(256) void k_build_wcx(
  const float* __restrict__ Wctx, unsigned short* WCx)
{
  const int idx = blockIdx.x*256 + threadIdx.x;     // 512*1024
  const int n = idx >> 10, k = idx & 1023;
  const int fn = n >> 4, l16 = n & 15;
  const int ks = k >> 5, qdd = (k >> 3) & 3, jj = k & 7;
  WCx[(((size_t)fn*32 + ks)*64 + qdd*16 + l16)*8 + jj] = f2bf(Wctx[(size_t)n*1024 + k]);
}

// W_src^T interleaved for the q matvec: element (e, d) at [(d>>3)*512+e]*8+(d&7)
__global__ __launch_bounds__(256) void k_build_wqt(
  const float* __restrict__ Wsrc, unsigned short* WQT)
{
  const int idx = blockIdx.x*256 + threadIdx.x;     // 512*512
  const int d = idx >> 9, e = idx & 511;
  WQT[((size_t)(d >> 3)*512 + e)*8 + (d & 7)] = f2bf(Wsrc[(size_t)d*512 + e]);
}

__global__ __launch_bounds__(256) void k_build_bias(
  const float* __restrict__ ebF, const float* __restrict__ ebB,
  const float* __restrict__ dB, float* bF, float* bB, float* bD)
{
  const int idx = blockIdx.x*256 + threadIdx.x;     // 4096
  if (idx < 1024) bF[idx] = ebF[(idx&3)*256 + (idx>>2)];
  else if (idx < 2048){ const int i = idx-1024; bB[i] = ebB[(i&3)*256 + (i>>2)]; }
  else { const int i = idx-2048; bD[i] = dB[(i&3)*512 + (i>>2)]; }
}

__global__ __launch_bounds__(256) void k_embed(
  const int* __restrict__ in_seq, const float* __restrict__ table, unsigned short* emb)
{
  const int idx = blockIdx.x*256 + threadIdx.x;     // S*B*256, layout (S,B,E)
  const int e = idx & 255, b = (idx >> 8) & 127, s = idx >> 15;
  const int tok = in_seq[b*S + s];
  emb[idx] = f2bf(table[(size_t)tok*256 + e]);
}

__global__ __launch_bounds__(256) void k_win(
  const float* __restrict__ tgt, unsigned short* win)
{
  const int idx = blockIdx.x*256 + threadIdx.x;     // T*B*64, layout (T,B,64)
  const int c = idx & 63, b = (idx >> 6) & 127, t = idx >> 13;
  float v = 0.f;
  if (c < 16){
    const int k = c >> 2, jj = c & 3;
    const int ts = t + k - 4;
    if (ts >= 0) v = tgt[((size_t)b*T + ts)*4 + jj];
  }
  win[idx] = f2bf(v);
}

// ---------------------------------------------------------------------------
extern "C" void kernel_launch(void* const* d_in, const int* in_sizes, int n_in,
                              void* d_out, int out_size, void* d_ws, size_t ws_size,
                              hipStream_t stream)
{
  const int*   in_seq    = (const int*)d_in[0];
  const float* tgt       = (const float*)d_in[1];
  // d_in[2] = lengths (unused by reference)
  const float* embedding = (const float*)d_in[3];
  const float* eWihF = (const float*)d_in[4];
  const float* eWhhF = (const float*)d_in[5];
  const float* ebF   = (const float*)d_in[6];
  const float* eWihB = (const float*)d_in[7];
  const float* eWhhB = (const float*)d_in[8];
  const float* ebB   = (const float*)d_in[9];
  const float* dWih  = (const float*)d_in[10];
  const float* dWhh  = (const float*)d_in[11];
  const float* dB    = (const float*)d_in[12];
  const float* Wsrc  = (const float*)d_in[13];
  const float* Wctx  = (const float*)d_in[14];
  const float* Wout  = (const float*)d_in[15];
  const float* bout  = (const float*)d_in[16];

  char* ws = (char*)d_ws;
  size_t off = 0;
  auto al = [&](size_t bytes)->char*{
    char* p = ws + off; off += (bytes + 255) & ~(size_t)255; return p; };

  // --- state region (zeroed every launch with one memset) ---
  char* stateBase = ws;
  unsigned short* hEnc = (unsigned short*)al(262144);  // [2][2][128][256]
  unsigned short* hdec = (unsigned short*)al(262144);  // [2][128][512]
  unsigned short* feed = (unsigned short*)al(131072);  // [128][512]
  unsigned short* ctxb = (unsigned short*)al(131072);  // [128][512]
  unsigned*       cnts = (unsigned*)al(20480);         // 160 counter lines
  unsigned*       pf   = (unsigned*)al(1024);          // [128][2] pair flags
  const size_t stateBytes = off;

  // --- persistent-per-launch scratch (fully rewritten each launch) ---
  unsigned short* emb    = (unsigned short*)al(16777216);  // (S,B,256) bf16
  unsigned short* win    = (unsigned short*)al(4194304);   // (T,B,64) bf16
  unsigned short* encOut = (unsigned short*)al(33554432);  // (B,S,512) bf16
  unsigned short* WFx    = (unsigned short*)al(1048576);   // swizzled 1024x512
  unsigned short* WBx    = (unsigned short*)al(1048576);
  unsigned short* WDx    = (unsigned short*)al(4456448);   // swizzled 2048x1088
  unsigned short* WCx    = (unsigned short*)al(1048576);   // swizzled 512x1024
  unsigned short* WQT    = (unsigned short*)al(524288);    // W_src^T interleaved
  float*          scp    = (float*)al(262144);             // [128][2][256]
  float* bFr = (float*)al(4096);
  float* bBr = (float*)al(4096);
  float* bDr = (float*)al(8192);
  (void)ws_size; (void)in_sizes; (void)n_in; (void)out_size;

  float* out_main = (float*)d_out;
  float* out_attn = out_main + (size_t)B*T*DOF;

  const dim3 blk(256);
  k_build_encw <<<4096,  blk, 0, stream>>>(eWihF, eWhhF, eWihB, eWhhB, WFx, WBx);
  k_build_decw <<<8704,  blk, 0, stream>>>(dWih, dWhh, WDx);
  k_build_wcx  <<<2048,  blk, 0, stream>>>(Wctx, WCx);
  k_build_wqt  <<<1024,  blk, 0, stream>>>(Wsrc, WQT);
  k_build_bias <<<16,    blk, 0, stream>>>(ebF, ebB, dB, bFr, bBr, bDr);
  k_embed      <<<32768, blk, 0, stream>>>(in_seq, embedding, emb);
  k_win        <<<8192,  blk, 0, stream>>>(tgt, win);
  hipMemsetAsync(stateBase, 0, stateBytes, stream);

  // persistent encoder: 256 steps internally
  k_encoder<<<256, blk, 0, stream>>>(emb, WFx, WBx, bFr, bBr, hEnc, encOut, cnts);

  // persistent decoder: 256 steps internally (encOut LDS-resident)
  k_decoder<<<256, blk, 0, stream>>>(win, WDx, bDr, WCx, WQT, encOut, in_seq,
                                     Wout, bout, hdec, feed, ctxb, scp, pf,
                                     out_main, out_attn, cnts);
}

// Round 6
// 11539.433 us; speedup vs baseline: 1.1749x; 1.1749x over previous
//
#include <hip/hip_runtime.h>
#include <stdint.h>

// Problem constants (match reference)
#define B 128
#define S 256
#define T 256
#define EMBED 256
#define ENC 256
#define DEC 512
#define DOF 4

typedef __attribute__((ext_vector_type(8))) short bf16x8;   // 8 bf16 = 4 VGPRs
typedef __attribute__((ext_vector_type(4))) float f32x4;    // MFMA C/D frag

static __device__ __forceinline__ float bf2f(unsigned short u){
  union{uint32_t u;float f;}c; c.u = ((uint32_t)u)<<16; return c.f;
}
static __device__ __forceinline__ unsigned short f2bf(float f){
  union{float f;uint32_t u;}c; c.f=f; uint32_t u=c.u;
  u += 0x7fffu + ((u>>16)&1u);  // round-to-nearest-even
  return (unsigned short)(u>>16);
}
static __device__ __forceinline__ void unp2(uint32_t w, float&a, float&b){
  union{uint32_t u;float f;}c1,c2; c1.u = w<<16; c2.u = w & 0xffff0000u; a=c1.f; b=c2.f;
}
static __device__ __forceinline__ float sigm(float x){ return 1.0f/(1.0f+__expf(-x)); }

// ---------------------------------------------------------------------------
// Ring-buffer protocol: cross-step state (h, feed, ctx) is write-once per
// launch (slot t+1). Producers store with agent-scope atomics (bypass L1/L2,
// land at the coherent point). Consumers use PLAIN CACHED loads: the address
// is first touched only after the barrier, so no stale line can exist
// (kernel-start acquire invalidated prior-kernel lines; stc8 never allocates
// in any L2). This turns the per-step state traffic into L2 hits.
// ---------------------------------------------------------------------------
static __device__ __forceinline__ void stc8(void* p, unsigned long long v){
  __hip_atomic_store((unsigned long long*)p, v, __ATOMIC_RELAXED, __HIP_MEMORY_SCOPE_AGENT);
}
static __device__ __forceinline__ void stc4(void* p, unsigned v){
  __hip_atomic_store((unsigned*)p, v, __ATOMIC_RELAXED, __HIP_MEMORY_SCOPE_AGENT);
}
static __device__ __forceinline__ unsigned ldc4(const void* p){
  return __hip_atomic_load((const unsigned*)p, __ATOMIC_RELAXED, __HIP_MEMORY_SCOPE_AGENT);
}
static __device__ __forceinline__ void stc4f(float* p, float v){ stc4(p, __float_as_uint(v)); }
static __device__ __forceinline__ float ldc4f(const float* p){ return __uint_as_float(ldc4(p)); }
union F16x8 { unsigned long long q[2]; bf16x8 v; unsigned short s[8]; };
union Ubf   { bf16x8 v; uint32_t u[4]; unsigned short s[8]; };
static __device__ __forceinline__ unsigned long long pack4bf(float a,float b,float c,float d){
  return (unsigned long long)f2bf(a) | ((unsigned long long)f2bf(b)<<16)
       | ((unsigned long long)f2bf(c)<<32) | ((unsigned long long)f2bf(d)<<48);
}

// ---------------------------------------------------------------------------
// Two-level device barrier (16 spread L1 lines -> 1 L2 line; single-lane poll)
// ---------------------------------------------------------------------------
#define CLINE 32   // u32 per counter line (128 B)
#define BAR_A   0
#define BAR_C   18
#define BAR_F   36
#define BAR_ENC 64   // 4 domains x 18 lines

static __device__ __forceinline__ void bar_pub(unsigned* base, int line,
                                               unsigned perline, unsigned epoch){
  __builtin_amdgcn_s_waitcnt(0);     // drain this wave's coherent stores
  __syncthreads();                   // all waves drained
  if (threadIdx.x == 0){
    unsigned old = __hip_atomic_fetch_add(base + (size_t)line*CLINE, 1u,
                                          __ATOMIC_RELAXED, __HIP_MEMORY_SCOPE_AGENT);
    if (old + 1u == perline*epoch)
      __hip_atomic_fetch_add(base + (size_t)16*CLINE, 1u,
                             __ATOMIC_RELAXED, __HIP_MEMORY_SCOPE_AGENT);
  }
}
static __device__ __forceinline__ void bar_wait(unsigned* base, unsigned epoch){
  if (threadIdx.x == 0){
    while (__hip_atomic_load(base + (size_t)16*CLINE,
                             __ATOMIC_RELAXED, __HIP_MEMORY_SCOPE_AGENT) < 16u*epoch)
      __builtin_amdgcn_s_sleep(2);
  }
  __syncthreads();
  asm volatile("" ::: "memory");
}

// swizzled LDS index (in shorts) for encS: row s (0..255), 16B-chunk c (0..31)
static __device__ __forceinline__ int enc_idx(int s, int c){
  return s*256 + (((c & 24) | ((c ^ s) & 7)) << 3);
}

// ---------------------------------------------------------------------------
// Persistent bi-LSTM encoder. Grid 256 = dir(2) x mg(2) x ng(64).
// Weight frags persist in registers; c in registers; h in ring encR
// [slot][dir][B][256] (slot 0 pre-zeroed). 4 independent barrier domains.
// ---------------------------------------------------------------------------
__global__ __launch_bounds__(256,1) void k_encoder(
  const unsigned short* __restrict__ emb,   // (S,B,256)
  const unsigned short* __restrict__ WFx, const unsigned short* __restrict__ WBx,
  const float* __restrict__ bF, const float* __restrict__ bB,
  unsigned short* __restrict__ encR,        // ring [257][2][B][256]
  unsigned short* __restrict__ encOut,      // [B][S][512]
  unsigned* __restrict__ cnts)
{
  __shared__ __align__(16) float Gs[64*17];
  __shared__ float bsh[16];
  const int bid = blockIdx.x;
  const int dir = bid >> 7;
  const int mg  = (bid >> 6) & 1;
  const int ng  = bid & 63;
  const int tid = threadIdx.x;
  const int lane = tid & 63, w = tid >> 6;
  const int l16 = lane & 15, qd = lane >> 4;
  const int m_base = mg * 64;
  unsigned* base = cnts + (size_t)(BAR_ENC + (dir*2 + mg)*18)*CLINE;

  const unsigned short* Bp = (dir ? WBx : WFx) + (size_t)ng*16*512 + (size_t)lane*8;
  bf16x8 Bv[16];
#pragma unroll
  for (int ks = 0; ks < 16; ++ks) Bv[ks] = *(const bf16x8*)(Bp + (size_t)ks*512);
  if (tid < 16) bsh[tid] = (dir ? bB : bF)[ng*16 + tid];
  float c[4] = {0.f,0.f,0.f,0.f};
  __syncthreads();

  for (int t = 0; t < S; ++t){
    const int tt = dir ? (S-1-t) : t;
    const unsigned short* Ae = emb + ((size_t)tt*B + m_base + w*16 + l16)*256 + qd*8;
    bf16x8 av[8];
#pragma unroll
    for (int ks = 0; ks < 8; ++ks) av[ks] = *(const bf16x8*)(Ae + ks*32);   // cached prefetch
    if (t) bar_wait(base, (unsigned)t);
    // h_{t-1} = ring slot t (plain cached loads, first-touch-after-barrier)
    const unsigned short* Ah = encR + (((size_t)t*2 + dir)*B + m_base + w*16 + l16)*256 + qd*8;
    f32x4 acc = (f32x4){0.f,0.f,0.f,0.f};
#pragma unroll
    for (int ks = 0; ks < 8; ++ks)
      acc = __builtin_amdgcn_mfma_f32_16x16x32_bf16(av[ks], Bv[ks], acc, 0, 0, 0);
#pragma unroll
    for (int ks = 0; ks < 8; ++ks){
      bf16x8 hf = *(const bf16x8*)(Ah + ks*32);
      acc = __builtin_amdgcn_mfma_f32_16x16x32_bf16(hf, Bv[8+ks], acc, 0, 0, 0);
    }
    __syncthreads();
#pragma unroll
    for (int r = 0; r < 4; ++r)
      Gs[(w*16 + qd*4 + r)*17 + l16] = acc[r];
    __syncthreads();
    if (tid < 64){
      float hv[4];
#pragma unroll
      for (int u = 0; u < 4; ++u){
        const float gi = Gs[tid*17 + u*4 + 0] + bsh[u*4 + 0];
        const float gf = Gs[tid*17 + u*4 + 1] + bsh[u*4 + 1];
        const float gg = Gs[tid*17 + u*4 + 2] + bsh[u*4 + 2];
        const float go = Gs[tid*17 + u*4 + 3] + bsh[u*4 + 3];
        const float cn = sigm(gf)*c[u] + sigm(gi)*tanhf(gg);
        c[u] = cn;
        hv[u] = sigm(go)*tanhf(cn);
      }
      const int b2 = m_base + tid;
      const unsigned long long hq = pack4bf(hv[0],hv[1],hv[2],hv[3]);
      stc8(&encR[(((size_t)(t+1)*2 + dir)*B + b2)*256 + ng*4], hq);
      *(unsigned long long*)&encOut[((size_t)b2*S + tt)*512 + dir*256 + ng*4] = hq;
    }
    bar_pub(base, ng & 15, 4u, (unsigned)(t+1));
  }
}

// ---------------------------------------------------------------------------
// Persistent decoder. Grid 256; block i owns (batch b=i>>1, e-half eh=i&1),
// encOut[b,:,eh-half] swizzled in LDS (128 KB) all 256 steps. Gate weights
// persist in registers. State rings: hR/fR/cR [257][B][512], slot t+1.
// Step: [waitF] gates -> barA -> [outproj] -> waitA ->
//       attention (q matvec + scores + pair-flag + softmax + ctx) -> barC ->
//       [64 blocks: waitC -> feed MFMA -> barF].
// ---------------------------------------------------------------------------
__global__ __launch_bounds__(256,1) void k_decoder(
  const unsigned short* __restrict__ win,    // (T,B,64)
  const unsigned short* __restrict__ WDx,    // swizzled gates weights
  const float* __restrict__ bD,              // 2048 reordered
  const unsigned short* __restrict__ WCx,    // swizzled W_ctx
  const unsigned short* __restrict__ WQT,    // W_src^T interleaved for matvec
  const unsigned short* __restrict__ encOut, // (B,S,512)
  const int* __restrict__ in_seq,
  const float* __restrict__ Wout, const float* __restrict__ bout,
  unsigned short* __restrict__ hR,           // ring [257][B][512]
  unsigned short* __restrict__ fR,           // ring [257][B][512]
  unsigned short* __restrict__ cR,           // ring [257][B][512]
  float* __restrict__ scp,                   // [B][2][256] partial scores (coherent)
  unsigned* __restrict__ pf,                 // [B*2] epoch flags, CLINE stride
  float* __restrict__ out_main, float* __restrict__ out_attn,
  unsigned* __restrict__ cnts)
{
  __shared__ __align__(16) unsigned short encS[65536];  // 128 KB resident tile
  __shared__ __align__(16) float scrf[1600];
  __shared__ float bsh[16];
  unsigned* barA = cnts + (size_t)BAR_A*CLINE;
  unsigned* barC = cnts + (size_t)BAR_C*CLINE;
  unsigned* barF = cnts + (size_t)BAR_F*CLINE;
  const int bid = blockIdx.x;
  const int b  = bid >> 1, eh = bid & 1;
  const int mg = bid & 1, ng = (bid >> 1) & 127;
  const int tid = threadIdx.x;
  const int lane = tid & 63, w = tid >> 6;
  const int l16 = lane & 15, qd = lane >> 4;
  const int m_base = mg*64;

  if (tid < 16) bsh[tid] = bD[ng*16 + tid];
  const int mymask = (in_seq[b*S + tid] == 0);
  const unsigned short* Bp = WDx + (size_t)ng*34*512 + (size_t)lane*8;
  bf16x8 WBv[34];
#pragma unroll
  for (int ks = 0; ks < 34; ++ks) WBv[ks] = *(const bf16x8*)(Bp + (size_t)ks*512);
  for (int i = 0; i < 32; ++i){
    const int s = i*8 + (tid>>5), cc = tid & 31;
    const uint4 v = *(const uint4*)&encOut[((size_t)b*S + s)*512 + eh*256 + cc*8];
    *(uint4*)&encS[enc_idx(s, cc)] = v;
  }
  float c[4] = {0.f,0.f,0.f,0.f};
  const bool doFeed = ((bid & 3) == 3);
  const int  fblk = bid >> 2, fm = fblk >> 5, fn = fblk & 31;
  __syncthreads();

  for (int t = 0; t < T; ++t){
    const int row = m_base + w*16 + l16;
    const unsigned short* Aw = win + ((size_t)t*B + row)*64 + qd*8;
    bf16x8 wv0 = *(const bf16x8*)(Aw);         // cached prefetch (read-only)
    bf16x8 wv1 = *(const bf16x8*)(Aw + 32);
    if (t) bar_wait(barF, (unsigned)t);        // feed_{t-1} ready
    // ---------------- phase A: gates + LSTM update ----------------
    const unsigned short* Af = fR + ((size_t)t*B + row)*512 + qd*8;  // feed_{t-1}
    const unsigned short* Ah = hR + ((size_t)t*B + row)*512 + qd*8;  // h_{t-1}
    f32x4 acc = (f32x4){0.f,0.f,0.f,0.f};
    {
      bf16x8 av[17];
      av[0] = wv0; av[1] = wv1;
#pragma unroll
      for (int i = 0; i < 15; ++i) av[2+i] = *(const bf16x8*)(Af + i*32);
#pragma unroll
      for (int ks = 0; ks < 17; ++ks)
        acc = __builtin_amdgcn_mfma_f32_16x16x32_bf16(av[ks], WBv[ks], acc, 0, 0, 0);
    }
    {
      bf16x8 av[17];
      av[0] = *(const bf16x8*)(Af + 15*32);
#pragma unroll
      for (int i = 0; i < 16; ++i) av[1+i] = *(const bf16x8*)(Ah + i*32);
#pragma unroll
      for (int ks = 0; ks < 17; ++ks)
        acc = __builtin_amdgcn_mfma_f32_16x16x32_bf16(av[ks], WBv[17+ks], acc, 0, 0, 0);
    }
    __syncthreads();
#pragma unroll
    for (int r = 0; r < 4; ++r)
      scrf[(w*16 + qd*4 + r)*17 + l16] = acc[r];
    __syncthreads();
    if (tid < 64){
      float hv[4];
#pragma unroll
      for (int u = 0; u < 4; ++u){
        const float gi = scrf[tid*17 + u*4 + 0] + bsh[u*4 + 0];
        const float gf = scrf[tid*17 + u*4 + 1] + bsh[u*4 + 1];
        const float gg = scrf[tid*17 + u*4 + 2] + bsh[u*4 + 2];
        const float go = scrf[tid*17 + u*4 + 3] + bsh[u*4 + 3];
        const float cn = sigm(gf)*c[u] + sigm(gi)*tanhf(gg);
        c[u] = cn;
        hv[u] = sigm(go)*tanhf(cn);
      }
      stc8(&hR[((size_t)(t+1)*B + m_base + tid)*512 + ng*4],
           pack4bf(hv[0],hv[1],hv[2],hv[3]));
    }
    bar_pub(barA, bid & 15, 16u, (unsigned)(t+1));

    // out-projection of feed_{t-1} (overlaps others' barA wait; odd blocks)
    if ((bid & 1) && t > 0){
      const int b2o = bid >> 1;
      const int d = tid >> 6, kk = lane;
      F16x8 u; u.v = *(const bf16x8*)(fR + ((size_t)t*B + b2o)*512 + kk*8);
      const float* wp = Wout + d*512 + kk*8;
      float p = 0.f;
#pragma unroll
      for (int j2 = 0; j2 < 8; ++j2) p += bf2f(u.s[j2]) * wp[j2];
#pragma unroll
      for (int off = 32; off > 0; off >>= 1) p += __shfl_down(p, off, 64);
      if (kk == 0){
        const float v = p + bout[d];
        out_main[((size_t)b2o*T + (t-1))*4 + d] = (d < 3) ? tanhf(v) : fmaxf(v, 0.f);
      }
    }

    // ---------------- attention (all blocks; e-half of batch b) ------------
    bar_wait(barA, (unsigned)(t+1));           // full h_t
    {  // stage h_t[b] into LDS hsh = scrf[1024..1535] (plain cached)
      const unsigned short* hsrc = hR + ((size_t)(t+1)*B + b)*512;
      if (tid < 128){
        F16x8 u; u.q[0] = *(const unsigned long long*)(hsrc + tid*4);
#pragma unroll
        for (int j2 = 0; j2 < 4; ++j2) scrf[1024 + tid*4 + j2] = bf2f(u.s[j2]);
      }
    }
    __syncthreads();
    {  // q matvec: thread computes q[e], e = eh*256 + tid (WQT L2-hot)
      float qv = 0.f;
      const int e = eh*256 + tid;
#pragma unroll 8
      for (int k8 = 0; k8 < 64; ++k8){
        Ubf u8; u8.v = *(const bf16x8*)&WQT[(size_t)(k8*512 + e)*8];
        float f0,f1,f2,f3,f4,f5,f6,f7;
        unp2(u8.u[0],f0,f1); unp2(u8.u[1],f2,f3); unp2(u8.u[2],f4,f5); unp2(u8.u[3],f6,f7);
        const float* hp = &scrf[1024 + k8*8];
        qv += f0*hp[0] + f1*hp[1] + f2*hp[2] + f3*hp[3]
            + f4*hp[4] + f5*hp[5] + f6*hp[6] + f7*hp[7];
      }
      scrf[tid] = qv;   // qsh
    }
    __syncthreads();
    float sc = 0.f;
#pragma unroll 8
    for (int cix = 0; cix < 32; ++cix){
      Ubf u8; u8.v = *(const bf16x8*)&encS[enc_idx(tid, cix)];
      float f0,f1,f2,f3,f4,f5,f6,f7;
      unp2(u8.u[0],f0,f1); unp2(u8.u[1],f2,f3); unp2(u8.u[2],f4,f5); unp2(u8.u[3],f6,f7);
      const float* qp = &scrf[cix*8];
      sc += f0*qp[0] + f1*qp[1] + f2*qp[2] + f3*qp[3]
          + f4*qp[4] + f5*qp[5] + f6*qp[6] + f7*qp[7];
    }
    stc4f(&scp[((size_t)b*2 + eh)*256 + tid], sc);
    // pair sync via single-writer epoch flags, ONE CACHE LINE PER FLAG
    __builtin_amdgcn_s_waitcnt(0);
    __syncthreads();
    if (tid == 0){
      stc4(&pf[(size_t)(b*2 + eh)*CLINE], (unsigned)(t+1));
      while (ldc4(&pf[(size_t)(b*2 + (1-eh))*CLINE]) < (unsigned)(t+1))
        __builtin_amdgcn_s_sleep(1);
    }
    __syncthreads();
    asm volatile("" ::: "memory");
    float tot = sc + ldc4f(&scp[((size_t)b*2 + (1-eh))*256 + tid]);
    if (mymask) tot = -1e30f;
    // softmax over 256 s
    float mx = tot;
#pragma unroll
    for (int off = 32; off > 0; off >>= 1) mx = fmaxf(mx, __shfl_xor(mx, off, 64));
    if (lane == 0) scrf[512 + w] = mx;
    __syncthreads();
    mx = fmaxf(fmaxf(scrf[512], scrf[513]), fmaxf(scrf[514], scrf[515]));
    const float e = __expf(tot - mx);
    float l = e;
#pragma unroll
    for (int off = 32; off > 0; off >>= 1) l += __shfl_xor(l, off, 64);
    if (lane == 0) scrf[516 + w] = l;
    __syncthreads();
    l = scrf[516] + scrf[517] + scrf[518] + scrf[519];
    const float aw = e / l;
    scrf[256 + tid] = aw;
    if (eh == 0) __builtin_nontemporal_store(aw, &out_attn[((size_t)b*T + t)*S + tid]);
    __syncthreads();
    // ctx e-half: wave w covers 64 s rows (2/iter), lane owns 8-e chunk
    {
      float a[8] = {0,0,0,0,0,0,0,0};
      const int cc = lane & 31, par = lane >> 5;
      for (int i2 = 0; i2 < 32; ++i2){
        const int srow = w*64 + i2*2 + par;
        const float wgt = scrf[256 + srow];
        Ubf u8; u8.v = *(const bf16x8*)&encS[enc_idx(srow, cc)];
        float f0,f1,f2,f3,f4,f5,f6,f7;
        unp2(u8.u[0],f0,f1); unp2(u8.u[1],f2,f3); unp2(u8.u[2],f4,f5); unp2(u8.u[3],f6,f7);
        a[0]+=wgt*f0; a[1]+=wgt*f1; a[2]+=wgt*f2; a[3]+=wgt*f3;
        a[4]+=wgt*f4; a[5]+=wgt*f5; a[6]+=wgt*f6; a[7]+=wgt*f7;
      }
#pragma unroll
      for (int j2 = 0; j2 < 8; ++j2) a[j2] += __shfl_xor(a[j2], 32, 64);
      if (par == 0){
#pragma unroll
        for (int j2 = 0; j2 < 8; ++j2) scrf[528 + w*256 + cc*8 + j2] = a[j2];
      }
    }
    __syncthreads();
    if (tid < 128){
      const int e2 = tid*2;
      const float s0 = scrf[528+e2]   + scrf[528+256+e2]   + scrf[528+512+e2]   + scrf[528+768+e2];
      const float s1 = scrf[528+e2+1] + scrf[528+256+e2+1] + scrf[528+512+e2+1] + scrf[528+768+e2+1];
      stc4(&cR[((size_t)(t+1)*B + b)*512 + eh*256 + e2],
           (unsigned)f2bf(s0) | ((unsigned)f2bf(s1) << 16));
    }
    bar_pub(barC, bid & 15, 16u, (unsigned)(t+1));

    // ---------------- phase F: feed = tanh([h|ctx] @ W_ctx^T) (64 blocks) ---
    if (doFeed){
      bar_wait(barC, (unsigned)(t+1));
      const int frow = fm*64 + w*16 + l16;
      const unsigned short* Fh = hR + ((size_t)(t+1)*B + frow)*512 + qd*8;
      const unsigned short* Fc = cR + ((size_t)(t+1)*B + frow)*512 + qd*8;
      const unsigned short* Bf = WCx + (size_t)fn*32*512 + (size_t)lane*8;
      f32x4 fa = (f32x4){0.f,0.f,0.f,0.f};
      {
        bf16x8 bv[16], av[16];
#pragma unroll
        for (int ks = 0; ks < 16; ++ks) bv[ks] = *(const bf16x8*)(Bf + (size_t)ks*512);
#pragma unroll
        for (int ks = 0; ks < 16; ++ks) av[ks] = *(const bf16x8*)(Fh + ks*32);
#pragma unroll
        for (int ks = 0; ks < 16; ++ks)
          fa = __builtin_amdgcn_mfma_f32_16x16x32_bf16(av[ks], bv[ks], fa, 0, 0, 0);
      }
      {
        bf16x8 bv[16], av[16];
#pragma unroll
        for (int ks = 0; ks < 16; ++ks) bv[ks] = *(const bf16x8*)(Bf + (size_t)(16+ks)*512);
#pragma unroll
        for (int ks = 0; ks < 16; ++ks) av[ks] = *(const bf16x8*)(Fc + ks*32);
#pragma unroll
        for (int ks = 0; ks < 16; ++ks)
          fa = __builtin_amdgcn_mfma_f32_16x16x32_bf16(av[ks], bv[ks], fa, 0, 0, 0);
      }
      __syncthreads();
#pragma unroll
      for (int r = 0; r < 4; ++r)
        scrf[(w*16 + qd*4 + r)*17 + l16] = tanhf(fa[r]);
      __syncthreads();
      if (tid < 64){
        const int fb = fm*64 + tid;
#pragma unroll
        for (int u = 0; u < 4; ++u)
          stc8(&fR[((size_t)(t+1)*B + fb)*512 + fn*16 + u*4],
               pack4bf(scrf[tid*17+u*4+0], scrf[tid*17+u*4+1],
                       scrf[tid*17+u*4+2], scrf[tid*17+u*4+3]));
      }
      bar_pub(barF, (bid >> 2) & 15, 4u, (unsigned)(t+1));
    }
  }
  // final out-projection (feed_255 = ring slot 256)
  if (bid & 1){
    bar_wait(barF, 256u);
    const int b2o = bid >> 1;
    const int d = tid >> 6, kk = lane;
    F16x8 u; u.v = *(const bf16x8*)(fR + ((size_t)256*B + b2o)*512 + kk*8);
    const float* wp = Wout + d*512 + kk*8;
    float p = 0.f;
#pragma unroll
    for (int j2 = 0; j2 < 8; ++j2) p += bf2f(u.s[j2]) * wp[j2];
#pragma unroll
    for (int off = 32; off > 0; off >>= 1) p += __shfl_down(p, off, 64);
    if (kk == 0){
      const float v = p + bout[d];
      out_main[((size_t)b2o*T + 255)*4 + d] = (d < 3) ? tanhf(v) : fmaxf(v, 0.f);
    }
  }
}

// ---------------- setup / builder kernels ----------------
__global__ __launch_bounds__(256) void k_build_encw(
  const float* __restrict__ WihF, const float* __restrict__ WhhF,
  const float* __restrict__ WihB, const float* __restrict__ WhhB,
  unsigned short* WFx, unsigned short* WBx)
{
  const int idx = blockIdx.x*256 + threadIdx.x;     // 2*1024*512
  const int dir = idx >> 19;
  const int i2 = idx & 524287;
  const int r = i2 >> 9, k = i2 & 511;
  const int j = r >> 2, g = r & 3;
  const int orig = g*256 + j;
  const float* Wih = dir ? WihB : WihF;
  const float* Whh = dir ? WhhB : WhhF;
  const float v = (k < 256) ? Wih[orig*256 + k] : Whh[orig*256 + (k-256)];
  const int ng = r >> 4, l16 = r & 15;
  const int ks = k >> 5, qdd = (k >> 3) & 3, jj = k & 7;
  (dir ? WBx : WFx)[(((size_t)ng*16 + ks)*64 + qdd*16 + l16)*8 + jj] = f2bf(v);
}

__global__ __launch_bounds__(256) void k_build_decw(
  const float* __restrict__ Wih, const float* __restrict__ Whh, unsigned short* WDx)
{
  const int idx = blockIdx.x*256 + threadIdx.x;
  if (idx >= 2048*1088) return;
  const int row = idx / 1088, col = idx - row*1088;
  const int j = row >> 2, g = row & 3;
  const int orig = g*512 + j;
  float v;
  if (col < 16)        v = Wih[orig*528 + col];          // w_t part
  else if (col < 64)   v = 0.f;                          // pad
  else if (col < 576)  v = Wih[orig*528 + (col - 48)];   // feed part
  else                 v = Whh[orig*512 + (col - 576)];  // h part
  const int ng = row >> 4, l16 = row & 15;
  const int ks = col >> 5, qdd = (col >> 3) & 3, jj = col & 7;
  WDx[(((size_t)ng*34 + ks)*64 + qdd*16 + l16)*8 + jj] = f2bf(v);
}

__global__ __launch_bounds__(256) void k_build_wcx(
  const float* __restrict__ Wctx, unsigned short* WCx)
{
  const int idx = blockIdx.x*256 + threadIdx.x;     // 512*1024
  const int n = idx >> 10, k = idx & 1023;
  const int fn = n >> 4, l16 = n & 15;
  const int ks = k >> 5, qdd = (k >> 3) & 3, jj = k & 7;
  WCx[(((size_t)fn*32 + ks)*64 + qdd*16 + l16)*8 + jj] = f2bf(Wctx[(size_t)n*1024 + k]);
}

__global__ __launch_bounds__(256) void k_build_wqt(
  const float* __restrict__ Wsrc, unsigned short* WQT)
{
  const int idx = blockIdx.x*256 + threadIdx.x;     // 512*512
  const int d = idx >> 9, e = idx & 511;
  WQT[((size_t)(d >> 3)*512 + e)*8 + (d & 7)] = f2bf(Wsrc[(size_t)d*512 + e]);
}

__global__ __launch_bounds__(256) void k_build_bias(
  const float* __restrict__ ebF, const float* __restrict__ ebB,
  const float* __restrict__ dB, float* bF, float* bB, float* bD)
{
  const int idx = blockIdx.x*256 + threadIdx.x;     // 4096
  if (idx < 1024) bF[idx] = ebF[(idx&3)*256 + (idx>>2)];
  else if (idx < 2048){ const int i = idx-1024; bB[i] = ebB[(i&3)*256 + (i>>2)]; }
  else { const int i = idx-2048; bD[i] = dB[(i&3)*512 + (i>>2)]; }
}

__global__ __launch_bounds__(256) void k_embed(
  const int* __restrict__ in_seq, const float* __restrict__ table, unsigned short* emb)
{
  const int idx = blockIdx.x*256 + threadIdx.x;     // S*B*256, layout (S,B,E)
  const int e = idx & 255, b = (idx >> 8) & 127, s = idx >> 15;
  const int tok = in_seq[b*S + s];
  emb[idx] = f2bf(table[(size_t)tok*256 + e]);
}

__global__ __launch_bounds__(256) void k_win(
  const float* __restrict__ tgt, unsigned short* win)
{
  const int idx = blockIdx.x*256 + threadIdx.x;     // T*B*64, layout (T,B,64)
  const int c = idx & 63, b = (idx >> 6) & 127, t = idx >> 13;
  float v = 0.f;
  if (c < 16){
    const int k = c >> 2, jj = c & 3;
    const int ts = t + k - 4;
    if (ts >= 0) v = tgt[((size_t)b*T + ts)*4 + jj];
  }
  win[idx] = f2bf(v);
}

// ---------------------------------------------------------------------------
extern "C" void kernel_launch(void* const* d_in, const int* in_sizes, int n_in,
                              void* d_out, int out_size, void* d_ws, size_t ws_size,
                              hipStream_t stream)
{
  const int*   in_seq    = (const int*)d_in[0];
  const float* tgt       = (const float*)d_in[1];
  // d_in[2] = lengths (unused by reference)
  const float* embedding = (const float*)d_in[3];
  const float* eWihF = (const float*)d_in[4];
  const float* eWhhF = (const float*)d_in[5];
  const float* ebF   = (const float*)d_in[6];
  const float* eWihB = (const float*)d_in[7];
  const float* eWhhB = (const float*)d_in[8];
  const float* ebB   = (const float*)d_in[9];
  const float* dWih  = (const float*)d_in[10];
  const float* dWhh  = (const float*)d_in[11];
  const float* dB    = (const float*)d_in[12];
  const float* Wsrc  = (const float*)d_in[13];
  const float* Wctx  = (const float*)d_in[14];
  const float* Wout  = (const float*)d_in[15];
  const float* bout  = (const float*)d_in[16];

  char* ws = (char*)d_ws;
  size_t off = 0;
  auto al = [&](size_t bytes)->char*{
    char* p = ws + off; off += (bytes + 255) & ~(size_t)255; return p; };

  // --- zeroed-per-launch control region ---
  char* ctrlBase = ws;
  unsigned* cnts = (unsigned*)al(20480);       // 160 counter lines
  unsigned* pf   = (unsigned*)al(32768);       // 256 flags x 128B line
  const size_t ctrlBytes = off;

  float*          scp  = (float*)al(262144);   // [B][2][256] fp32 (coherent)
  float* bFr = (float*)al(4096);
  float* bBr = (float*)al(4096);
  float* bDr = (float*)al(8192);
  unsigned short* win    = (unsigned short*)al(4194304);   // (T,B,64)
  unsigned short* encOut = (unsigned short*)al(33554432);  // (B,S,512)
  unsigned short* WDx    = (unsigned short*)al(4456448);   // swizzled 2048x1088
  unsigned short* WCx    = (unsigned short*)al(1048576);   // swizzled 512x1024
  unsigned short* WQT    = (unsigned short*)al(524288);    // W_src^T interleaved

  // --- ring regions (encoder-phase buffers aliased in front) ---
  const size_t RING = (size_t)257*B*512*2;                 // 33,685,504 B
  char* region0 = al(RING);   // encoder: encR ring | decoder: hR ring
  char* region1 = al(RING);   // encoder: emb (16.8MB) | decoder: fR ring
  char* region2 = al(RING);   // encoder: WFx+WBx (2MB) | decoder: cR ring
  unsigned short* encR = (unsigned short*)region0;
  unsigned short* hR   = (unsigned short*)region0;
  unsigned short* emb  = (unsigned short*)region1;
  unsigned short* fR   = (unsigned short*)region1;
  unsigned short* WFx  = (unsigned short*)region2;
  unsigned short* WBx  = (unsigned short*)(region2 + 1048576);
  unsigned short* cR   = (unsigned short*)region2;
  (void)ws_size; (void)in_sizes; (void)n_in; (void)out_size;

  float* out_main = (float*)d_out;
  float* out_attn = out_main + (size_t)B*T*DOF;

  const dim3 blk(256);
  k_build_encw <<<4096,  blk, 0, stream>>>(eWihF, eWhhF, eWihB, eWhhB, WFx, WBx);
  k_build_decw <<<8704,  blk, 0, stream>>>(dWih, dWhh, WDx);
  k_build_wcx  <<<2048,  blk, 0, stream>>>(Wctx, WCx);
  k_build_wqt  <<<1024,  blk, 0, stream>>>(Wsrc, WQT);
  k_build_bias <<<16,    blk, 0, stream>>>(ebF, ebB, dB, bFr, bBr, bDr);
  k_embed      <<<32768, blk, 0, stream>>>(in_seq, embedding, emb);
  k_win        <<<8192,  blk, 0, stream>>>(tgt, win);
  hipMemsetAsync(ctrlBase, 0, ctrlBytes, stream);
  hipMemsetAsync(region0, 0, 131072, stream);   // encR slot 0 (== hR slot 0 later)

  // persistent encoder: 256 steps internally
  k_encoder<<<256, blk, 0, stream>>>(emb, WFx, WBx, bFr, bBr, encR, encOut, cnts);

  hipMemsetAsync(region1, 0, 131072, stream);   // fR slot 0 (emb is dead now)

  // persistent decoder: 256 steps internally
  k_decoder<<<256, blk, 0, stream>>>(win, WDx, bDr, WCx, WQT, encOut, in_seq,
                                     Wout, bout, hR, fR, cR, scp, pf,
                                     out_main, out_attn, cnts);
}